// Round 3
// baseline (636.062 us; speedup 1.0000x reference)
//
#include <hip/hip_runtime.h>

typedef __bf16 bf16x8 __attribute__((ext_vector_type(8)));
typedef __bf16 bf16x4 __attribute__((ext_vector_type(4)));
typedef float  f32x4  __attribute__((ext_vector_type(4)));

#define DDEC  176
#define DSP   54
#define K1    222
#define K1P   224
#define HID   256
#define HSTR  264            // h row stride (bf16 elems): 528B, 16B-aligned, 2-way bank alias
#define RPW   16             // rows per wave
#define WPB   2              // waves per block
#define BM    (RPW * WPB)    // 32 rows per block

#define WT1_OFF 57344        // 256*224
#define WT2_OFF 122880       // + 256*256
#define MLP_WS  131072       // + 32*256  (bf16 elems per MLP)

struct Biases {
  const float* b1[3];
  const float* b2[3];
};

// ---- convert/transpose weights to bf16: Wt0[256][224] (b0 folded at k=222),
// Wt1[256][256], Wt2[32][256] per MLP
__global__ __launch_bounds__(256) void prep_weights(
    const float* __restrict__ w0a, const float* __restrict__ w1a, const float* __restrict__ w2a,
    const float* __restrict__ w0b, const float* __restrict__ w1b, const float* __restrict__ w2b,
    const float* __restrict__ w0c, const float* __restrict__ w1c, const float* __restrict__ w2c,
    const float* __restrict__ b0a, const float* __restrict__ b0b, const float* __restrict__ b0c,
    __bf16* __restrict__ ws)
{
  int idx = blockIdx.x * 256 + threadIdx.x;
  if (idx >= 3 * MLP_WS) return;
  int m = idx / MLP_WS;
  int r = idx - m * MLP_WS;
  const float* w0 = (m == 0) ? w0a : (m == 1) ? w0b : w0c;
  const float* w1 = (m == 0) ? w1a : (m == 1) ? w1b : w1c;
  const float* w2 = (m == 0) ? w2a : (m == 1) ? w2b : w2c;
  const float* b0 = (m == 0) ? b0a : (m == 1) ? b0b : b0c;
  float v;
  if (r < WT1_OFF) {                 // Wt0[n][k] = w0[k][n]; k=222 -> b0[n]; k=223 -> 0
    int n = r / K1P;
    int k = r - n * K1P;
    v = (k < K1) ? w0[k * HID + n] : (k == K1 ? b0[n] : 0.0f);
  } else if (r < WT2_OFF) {          // Wt1[n][k] = w1[k][n]
    int rr = r - WT1_OFF;
    int n = rr >> 8, k = rr & 255;
    v = w1[k * HID + n];
  } else {                           // Wt2[n][k] = w2[k][n], n padded to 32
    int rr = r - WT2_OFF;
    int n = rr >> 8, k = rr & 255;
    int od = (m == 0) ? 8 : 24;
    v = (n < od) ? w2[k * od + n] : 0.0f;
  }
  ws[idx] = (__bf16)v;
}

__device__ __forceinline__ bf16x8 pack8(float2 a, float2 b, float2 c, float2 d) {
  return (bf16x8){(__bf16)a.x, (__bf16)a.y, (__bf16)b.x, (__bf16)b.y,
                  (__bf16)c.x, (__bf16)c.y, (__bf16)d.x, (__bf16)d.y};
}

// Wave-independent fused trunk: each wave owns 16 rows x 256 cols.
// No __syncthreads anywhere: h round-trips through a wave-private LDS strip
// (in-order DS pipe + compiler waitcnt give the ordering).
__global__ __launch_bounds__(128, 4) void trunk_fused(
    const float* __restrict__ sparse, const float* __restrict__ dec,
    const __bf16* __restrict__ ws, float* __restrict__ out,
    Biases bp)
{
  __shared__ __align__(16) __bf16 hls[BM * HSTR];

  const int tid  = threadIdx.x;
  const int lane = tid & 63;
  const int wid  = tid >> 6;
  const int lr   = lane & 15;        // 16-dim index (frag row/col)
  const int lg   = lane >> 4;        // k/reg sub-group
  const long grow = (long)blockIdx.x * BM + wid * RPW + lr;
  __bf16* hrow = &hls[(wid * RPW + lr) * HSTR];

  // ---- gather x into registers: xreg[kp] = x[row][(kp*4+lg)*8 .. +8)
  // (exactly the MFMA B-fragment layout -> layer 0 needs no LDS at all)
  bf16x8 xreg[7];
  {
    const float* drow = dec + grow * DDEC;
    const float* srow = sparse + grow * DSP;
    // dec float-offsets (joint*8) packed per kp, 16-bit fields indexed by lg
    const unsigned long long D0 = 0ull  | (24ull << 16) | (48ull << 32) | (72ull << 48);
    const unsigned long long D1 = 96ull | (104ull << 16) | (112ull << 32) | (120ull << 48);
    const unsigned long long D2 = 128ull| (136ull << 16) | (144ull << 32) | (152ull << 48);
    const unsigned long long D3 = 160ull| (168ull << 16) | (152ull << 32) | (136ull << 48);
    const unsigned long long D4 = 112ull| (72ull  << 16) | (48ull  << 32) | (24ull  << 48);
    const unsigned long long DOFF[5] = {D0, D1, D2, D3, D4};
    #pragma unroll
    for (int kp = 0; kp < 5; ++kp) {
      int off = (int)((DOFF[kp] >> (lg * 16)) & 0xffffull);
      const float4* p = (const float4*)(drow + off);
      float4 a = p[0], b = p[1];
      xreg[kp] = (bf16x8){(__bf16)a.x, (__bf16)a.y, (__bf16)a.z, (__bf16)a.w,
                          (__bf16)b.x, (__bf16)b.y, (__bf16)b.z, (__bf16)b.w};
    }
    {  // kp=5: lg==0 -> dec joint 0; lg>=1 -> sparse[ (lg-1)*8 .. +8 )
      const float* p = (lg == 0) ? drow : (srow + (lg - 1) * 8);
      const float2* q = (const float2*)p;
      xreg[5] = pack8(q[0], q[1], q[2], q[3]);
    }
    {  // kp=6: lg<3 -> sparse[24+lg*8 ..); lg==3 -> sparse[48..53], 1.0 (b0 hook), 0
      const float* p = srow + 24 + lg * 8;
      const float2* q = (const float2*)p;
      float2 t = (lg < 3) ? q[3] : make_float2(1.0f, 0.0f);
      xreg[6] = pack8(q[0], q[1], q[2], t);
    }
  }

  for (int m = 0; m < 3; ++m) {
    const __bf16* wt0 = ws + m * MLP_WS;
    const __bf16* wt1 = wt0 + WT1_OFF;
    const __bf16* wt2 = wt0 + WT2_OFF;
    const int odim = (m == 0) ? 8 : 24;

    f32x4 acc[16];

    // ---- layer 0: h1^T = W0^T x^T   (K=224, bias folded at k=222)
    #pragma unroll
    for (int nb = 0; nb < 16; ++nb) acc[nb] = (f32x4){0.f, 0.f, 0.f, 0.f};
    {
      const __bf16* wbase = wt0 + (size_t)lr * K1P + lg * 8;
      #pragma unroll
      for (int kp = 0; kp < 7; ++kp) {
        #pragma unroll
        for (int nb = 0; nb < 16; ++nb) {
          bf16x8 a = *(const bf16x8*)(wbase + (size_t)nb * 16 * K1P + kp * 32);
          acc[nb] = __builtin_amdgcn_mfma_f32_16x16x32_bf16(a, xreg[kp], acc[nb], 0, 0, 0);
        }
      }
    }
    // epilogue: lrelu, pack 4 consecutive hidden cols, one b64 write each
    #pragma unroll
    for (int nb = 0; nb < 16; ++nb) {
      bf16x4 h;
      #pragma unroll
      for (int i = 0; i < 4; ++i) {
        float v = acc[nb][i];
        v = (v > 0.f) ? v : 0.01f * v;
        h[i] = (__bf16)v;
      }
      *(bf16x4*)(hrow + nb * 16 + lg * 4) = h;
    }

    // ---- layer 1: h2^T = W1^T h1^T + b1  (K=256); h2 overwrites h1 (same-wave,
    // in-order DS: all reads issue before the epilogue writes)
    #pragma unroll
    for (int nb = 0; nb < 16; ++nb) acc[nb] = (f32x4){0.f, 0.f, 0.f, 0.f};
    {
      const __bf16* wbase = wt1 + (size_t)lr * HID + lg * 8;
      #pragma unroll
      for (int kk = 0; kk < 8; ++kk) {
        bf16x8 bfr = *(const bf16x8*)(hrow + kk * 32 + lg * 8);
        #pragma unroll
        for (int nb = 0; nb < 16; ++nb) {
          bf16x8 a = *(const bf16x8*)(wbase + (size_t)nb * 16 * HID + kk * 32);
          acc[nb] = __builtin_amdgcn_mfma_f32_16x16x32_bf16(a, bfr, acc[nb], 0, 0, 0);
        }
      }
    }
    {
      const float* b1 = bp.b1[m];
      #pragma unroll
      for (int nb = 0; nb < 16; ++nb) {
        float4 bv = *(const float4*)(b1 + nb * 16 + lg * 4);
        bf16x4 h;
        #pragma unroll
        for (int i = 0; i < 4; ++i) {
          float v = acc[nb][i] + ((const float*)&bv)[i];
          v = (v > 0.f) ? v : 0.01f * v;
          h[i] = (__bf16)v;
        }
        *(bf16x4*)(hrow + nb * 16 + lg * 4) = h;
      }
    }

    // ---- layer 2: res^T = W2^T h2^T + b2  (out padded to 32 cols)
    f32x4 a2[2] = {(f32x4){0.f,0.f,0.f,0.f}, (f32x4){0.f,0.f,0.f,0.f}};
    {
      const __bf16* wbase = wt2 + (size_t)lr * HID + lg * 8;
      #pragma unroll
      for (int kk = 0; kk < 8; ++kk) {
        bf16x8 bfr = *(const bf16x8*)(hrow + kk * 32 + lg * 8);
        #pragma unroll
        for (int nb = 0; nb < 2; ++nb) {
          bf16x8 a = *(const bf16x8*)(wbase + (size_t)nb * 16 * HID + kk * 32);
          a2[nb] = __builtin_amdgcn_mfma_f32_16x16x32_bf16(a, bfr, a2[nb], 0, 0, 0);
        }
      }
    }
    const float* b2 = bp.b2[m];
    if (m == 2) {
      #pragma unroll
      for (int nb = 0; nb < 2; ++nb) {
        const int col0 = nb * 16 + lg * 4;
        if (col0 < 24) {
          float4 bv = *(const float4*)(b2 + col0);
          float4 o;
          o.x = a2[nb][0] + bv.x;
          o.y = a2[nb][1] + bv.y;
          o.z = a2[nb][2] + bv.z;
          o.w = a2[nb][3] + bv.w;
          *(float4*)(out + grow * 24 + col0) = o;
        }
      }
    } else {
      // write res (bias applied, bf16) into wave-private strip, then update xreg
      #pragma unroll
      for (int nb = 0; nb < 2; ++nb) {
        const int col0 = nb * 16 + lg * 4;
        if (col0 < odim) {
          float4 bv = *(const float4*)(b2 + col0);
          bf16x4 r;
          r[0] = (__bf16)(a2[nb][0] + bv.x);
          r[1] = (__bf16)(a2[nb][1] + bv.y);
          r[2] = (__bf16)(a2[nb][2] + bv.z);
          r[3] = (__bf16)(a2[nb][3] + bv.w);
          *(bf16x4*)(hrow + col0) = r;
        }
      }
      if (m == 0) {
        // res1 (joint 9, 8 vals) -> x chunks 3 (kp0,lg3) and 17 (kp4,lg1)
        bf16x8 r = *(const bf16x8*)(hrow + 0);
        if (lg == 3) xreg[0] = r;
        if (lg == 1) xreg[4] = r;
      } else {
        // res2: joint6 -> chunks 2 (kp0,lg2) & 18 (kp4,lg2);
        //       joint9 -> chunks 3 (kp0,lg3) & 17 (kp4,lg1); joint12 -> chunk 4 (kp1,lg0)
        const int off = (lg == 0) ? 16 : (lg == 2) ? 0 : 8;
        bf16x8 r = *(const bf16x8*)(hrow + off);
        if (lg == 0)      { xreg[1] = r; }
        else if (lg == 1) { xreg[4] = r; }
        else if (lg == 2) { xreg[0] = r; xreg[4] = r; }
        else              { xreg[0] = r; }
      }
    }
  }
}

extern "C" void kernel_launch(void* const* d_in, const int* in_sizes, int n_in,
                              void* d_out, int out_size, void* d_ws, size_t ws_size,
                              hipStream_t stream)
{
  const float* sparse = (const float*)d_in[0];
  const float* dec    = (const float*)d_in[1];
  Biases bp;
  const float* w0[3]; const float* w1[3]; const float* w2[3]; const float* b0[3];
  for (int m = 0; m < 3; ++m) {
    w0[m]    = (const float*)d_in[2 + m * 6 + 0];
    b0[m]    = (const float*)d_in[2 + m * 6 + 1];
    w1[m]    = (const float*)d_in[2 + m * 6 + 2];
    bp.b1[m] = (const float*)d_in[2 + m * 6 + 3];
    w2[m]    = (const float*)d_in[2 + m * 6 + 4];
    bp.b2[m] = (const float*)d_in[2 + m * 6 + 5];
  }
  __bf16* ws = (__bf16*)d_ws;
  const int nrows = in_sizes[0] / DSP;   // 131072 (divisible by BM=32)

  const int prep_total = 3 * MLP_WS;
  prep_weights<<<(prep_total + 255) / 256, 256, 0, stream>>>(
      w0[0], w1[0], w2[0], w0[1], w1[1], w2[1], w0[2], w1[2], w2[2],
      b0[0], b0[1], b0[2], ws);

  const int nblocks = nrows / BM;
  trunk_fused<<<nblocks, 128, 0, stream>>>(sparse, dec, ws, (float*)d_out, bp);
}